// Round 14
// baseline (24.829 us; speedup 1.0000x reference)
//
#include <hip/hip_runtime.h>
#include <math.h>

// ---------------------------------------------------------------------------
// DirectVoxGO Raw2Alpha + Alphas2Weights (forward), single fused kernel.
//
// outputs (concatenated in d_out, float32):
//   weights[n_pts]         = alpha_j * T_j,  T_j = prod_{k<j} (1-alpha_k)
//   alphainv_last[n_rays]  = prod over ray of (1-alpha)  (empty rays -> 1.0)
//
// Structure: 1 block (256 thr) owns 4096 consecutive points = TWO 2048-pt
// tiles, software-pipelined: ALL loads (tile A + tile B + lookback) issue at
// kernel start, so tile B's HBM latency hides under tile A's compute.
// Tile B needs no lookback: its head carry = tile A's trailing transmittance
// (free byproduct of tile A's segmented scan, thread 255's e[7]).
// XCD-aware bijective block swizzle keeps the lookback window L2-resident.
// Per-tile segmented multiplicative scan: thread-local fold -> wave64 DPP
// (value,flag) scan -> 4-wave LDS combine -> head-carry fold.
// ---------------------------------------------------------------------------

#define LOG2E 1.4426950408889634f
#define EPT   8                     // elements per thread (VGPR-safe)
#define TILE  (256 * EPT)           // 2048 points per tile
#define BPTS  (2 * TILE)            // 4096 points per block
#define WIN   256                   // lookback window width
#define NXCD  8

typedef float vf4 __attribute__((ext_vector_type(4)));

__device__ __forceinline__ float exp2f_(float x) { return __builtin_amdgcn_exp2f(x); }
__device__ __forceinline__ float log2f_(float x) { return __builtin_amdgcn_logf(x); }
__device__ __forceinline__ float rsqf_(float x)  { return __builtin_amdgcn_rsqf(x); }

__device__ __forceinline__ float oma(float d, float sh2, float negc, bool fast) {
    const float y = fmaf(d, LOG2E, sh2);
    if (fast) return rsqf_(1.0f + exp2f_(y));
    const float sp = fmaxf(y, 0.f) + log2f_(1.f + exp2f_(-fabsf(y)));
    return exp2f_(negc * sp);
}

// Segmented-scan DPP step: combine src (earlier lanes, identity (1,0) when
// out-of-row/masked) into (V,F):  V = F ? V : Vs*V;  F |= Fs.
template <int CTRL, int RM>
__device__ __forceinline__ void seg_step(float& V, int& F) {
    const int vs_i = __builtin_amdgcn_update_dpp(
        0x3f800000, __builtin_bit_cast(int, V), CTRL, RM, 0xF, false);
    const int fs = __builtin_amdgcn_update_dpp(0, F, CTRL, RM, 0xF, false);
    const float vs = __builtin_bit_cast(float, vs_i);
    V = F ? V : vs * V;
    F = F | fs;
}

// Full-wave product, result broadcast to all lanes.
__device__ __forceinline__ float wave_prod_bcast(float x) {
#define STEPP(CTRL, RM)                                                        \
    { int t_ = __builtin_amdgcn_update_dpp(0x3f800000,                         \
          __builtin_bit_cast(int, x), CTRL, RM, 0xF, false);                   \
      x *= __builtin_bit_cast(float, t_); }
    STEPP(0x111, 0xF) STEPP(0x112, 0xF) STEPP(0x114, 0xF)
    STEPP(0x118, 0xF) STEPP(0x142, 0xA) STEPP(0x143, 0xC)
#undef STEPP
    return __builtin_bit_cast(float,
        __builtin_amdgcn_readlane(__builtin_bit_cast(int, x), 63));
}

// Full-wave int max, result broadcast to all lanes.
__device__ __forceinline__ int wave_imax_bcast(int x) {
#define STEPM(CTRL, RM)                                                        \
    { int t_ = __builtin_amdgcn_update_dpp((int)0x80000000, x, CTRL, RM,       \
                                           0xF, false);                        \
      x = (x > t_) ? x : t_; }
    STEPM(0x111, 0xF) STEPM(0x112, 0xF) STEPM(0x114, 0xF)
    STEPM(0x118, 0xF) STEPM(0x142, 0xA) STEPM(0x143, 0xC)
#undef STEPM
    return __builtin_amdgcn_readlane(x, 63);
}

__global__ void __launch_bounds__(256)
fused_alpha_weights(const float* __restrict__ density,
                    const int*   __restrict__ ray_id,
                    const float* __restrict__ shift_p,
                    const float* __restrict__ interval_p,
                    float* __restrict__ weights,
                    float* __restrict__ alphainv,
                    int n_pts, int n_rays) {
    __shared__ float s_wv[4];
    __shared__ int   s_wf[4];
    __shared__ float s_red[4];
    __shared__ int   s_redi[4];
    __shared__ float s_tail;         // tile A trailing transmittance

    const int t    = threadIdx.x;
    const int lane = t & 63;
    const int wid  = t >> 6;

    // XCD-aware bijective swizzle (m204): XCD k owns a contiguous data chunk.
    const int nwg  = gridDim.x;
    const int orig = blockIdx.x;
    const int qq   = nwg / NXCD, rr = nwg % NXCD;
    const int xcd  = orig % NXCD;
    const int blk  = (xcd < rr ? xcd * (qq + 1) : rr * (qq + 1) + (xcd - rr) * qq)
                   + orig / NXCD;

    const int baseA = blk * BPTS;
    const int baseB = baseA + TILE;
    const int idxA  = baseA + t * EPT;
    const int idxB  = baseB + t * EPT;
    const bool haveB = (baseB < n_pts);

    const float shift = shift_p[0];
    const float c     = interval_p[0];
    const float sh2   = shift * LOG2E;
    const float negc  = -c;
    const bool  fast  = (c == 0.5f);

    // ================= phase 0: issue ALL loads up front =================
    int rA[EPT + 1]; float dA[EPT]; bool vA[EPT];
    if (idxA + EPT <= n_pts) {
        const int4   ri0 = *reinterpret_cast<const int4*>(ray_id + idxA);
        const int4   ri1 = *reinterpret_cast<const int4*>(ray_id + idxA + 4);
        const float4 de0 = *reinterpret_cast<const float4*>(density + idxA);
        const float4 de1 = *reinterpret_cast<const float4*>(density + idxA + 4);
        rA[0]=ri0.x; rA[1]=ri0.y; rA[2]=ri0.z; rA[3]=ri0.w;
        rA[4]=ri1.x; rA[5]=ri1.y; rA[6]=ri1.z; rA[7]=ri1.w;
        dA[0]=de0.x; dA[1]=de0.y; dA[2]=de0.z; dA[3]=de0.w;
        dA[4]=de1.x; dA[5]=de1.y; dA[6]=de1.z; dA[7]=de1.w;
        #pragma unroll
        for (int k = 0; k < EPT; ++k) vA[k] = true;
    } else {
        #pragma unroll
        for (int k = 0; k < EPT; ++k) {
            const int i = idxA + k;
            vA[k] = (i < n_pts);
            rA[k] = vA[k] ? ray_id[i] : n_rays;
            dA[k] = vA[k] ? density[i] : 0.0f;
        }
    }
    rA[EPT] = (idxA + EPT < n_pts) ? ray_id[idxA + EPT] : n_rays;
    const int rprevA = (idxA == 0) ? -1
                     : ((idxA <= n_pts) ? ray_id[idxA - 1] : n_rays);

    int rB[EPT + 1]; float dB[EPT]; bool vB[EPT];
    int rprevB = n_rays;
    if (haveB) {
        if (idxB + EPT <= n_pts) {
            const int4   ri0 = *reinterpret_cast<const int4*>(ray_id + idxB);
            const int4   ri1 = *reinterpret_cast<const int4*>(ray_id + idxB + 4);
            const float4 de0 = *reinterpret_cast<const float4*>(density + idxB);
            const float4 de1 = *reinterpret_cast<const float4*>(density + idxB + 4);
            rB[0]=ri0.x; rB[1]=ri0.y; rB[2]=ri0.z; rB[3]=ri0.w;
            rB[4]=ri1.x; rB[5]=ri1.y; rB[6]=ri1.z; rB[7]=ri1.w;
            dB[0]=de0.x; dB[1]=de0.y; dB[2]=de0.z; dB[3]=de0.w;
            dB[4]=de1.x; dB[5]=de1.y; dB[6]=de1.z; dB[7]=de1.w;
            #pragma unroll
            for (int k = 0; k < EPT; ++k) vB[k] = true;
        } else {
            #pragma unroll
            for (int k = 0; k < EPT; ++k) {
                const int i = idxB + k;
                vB[k] = (i < n_pts);
                rB[k] = vB[k] ? ray_id[i] : n_rays;
                dB[k] = vB[k] ? density[i] : 0.0f;
            }
        }
        rB[EPT] = (idxB + EPT < n_pts) ? ray_id[idxB + EPT] : n_rays;
        rprevB  = (idxB <= n_pts) ? ray_id[idxB - 1] : n_rays;
    } else {
        #pragma unroll
        for (int k = 0; k < EPT; ++k) { rB[k] = n_rays; dB[k] = 0.0f; vB[k] = false; }
        rB[EPT] = n_rays;
    }

    int w_id = 0; float w_den = 0.0f; int rfirst = 0;
    if (baseA > 0) {                             // speculative lookback window
        const int wi = baseA - WIN + t;
        w_id   = ray_id[wi];
        w_den  = density[wi];
        rfirst = ray_id[baseA];
    }

    // ================= tile A: values, flags, fold, wave scan =============
    float aA[EPT]; int fA[EPT];
    #pragma unroll
    for (int k = 0; k < EPT; ++k) {
        const float av = oma(dA[k], sh2, negc, fast);
        aA[k] = vA[k] ? av : 1.0f;
        fA[k] = (k == 0) ? (rA[0] != rprevA) : (rA[k] != rA[k - 1]);
    }

    float V = aA[0];  int F = fA[0];
    #pragma unroll
    for (int k = 1; k < EPT; ++k) {
        V = fA[k] ? aA[k] : V * aA[k];
        F |= fA[k];
    }

    float Vi = V;  int Fi = F;
    seg_step<0x111, 0xF>(Vi, Fi);
    seg_step<0x112, 0xF>(Vi, Fi);
    seg_step<0x114, 0xF>(Vi, Fi);
    seg_step<0x118, 0xF>(Vi, Fi);
    seg_step<0x142, 0xA>(Vi, Fi);
    seg_step<0x143, 0xC>(Vi, Fi);

    if (lane == 63) { s_wv[wid] = Vi; s_wf[wid] = Fi; }
    if (baseA > 0) {
        const int cand = (w_id != rfirst) ? t : -1;
        const int wm = wave_imax_bcast(cand);
        if (lane == 0) s_redi[wid] = wm;
    }
    __syncthreads();                             // barrier A1

    float carry0 = 1.0f;
    if (baseA > 0) {
        int m = s_redi[0];
        m = (s_redi[1] > m) ? s_redi[1] : m;
        m = (s_redi[2] > m) ? s_redi[2] : m;
        m = (s_redi[3] > m) ? s_redi[3] : m;
        float aa = oma(w_den, sh2, negc, fast);
        if (m >= 0 && t <= m) aa = 1.0f;
        const float wp = wave_prod_bcast(aa);
        if (lane == 0) s_red[wid] = wp;
        __syncthreads();                         // barrier A2
        carry0 = s_red[0] * s_red[1] * s_red[2] * s_red[3];

        if (m < 0) {                             // freak ray: walk further back
            int lo = baseA - WIN;
            int s0 = -1;
            while (s0 < 0) {
                const int wstart = lo - WIN;
                const int i = wstart + t;
                const int vv = (i >= 0) ? ray_id[i] : -1;
                const int c2 = (vv != rfirst) ? t : -1;
                const int wm2 = wave_imax_bcast(c2);
                if (lane == 0) s_redi[wid] = wm2;
                __syncthreads();
                int m2 = s_redi[0];
                m2 = (s_redi[1] > m2) ? s_redi[1] : m2;
                m2 = (s_redi[2] > m2) ? s_redi[2] : m2;
                m2 = (s_redi[3] > m2) ? s_redi[3] : m2;
                __syncthreads();
                if (m2 >= 0) s0 = wstart + m2 + 1; else lo = wstart;
            }
            for (int off = s0; off < baseA - WIN; off += WIN) {
                const int i = off + t;
                const float aa2 = (i < baseA - WIN)
                                ? oma(density[i], sh2, negc, fast) : 1.0f;
                const float wp2 = wave_prod_bcast(aa2);
                if (lane == 0) s_red[wid] = wp2;
                __syncthreads();
                carry0 *= s_red[0] * s_red[1] * s_red[2] * s_red[3];
                __syncthreads();
            }
        }
    }

    float Vx = __shfl_up(Vi, 1, 64);
    int   Fx = __shfl_up(Fi, 1, 64);
    if (lane == 0) { Vx = 1.0f; Fx = 0; }

    float Ev = carry0;
    #pragma unroll
    for (int w2 = 0; w2 < 3; ++w2) {
        if (w2 < wid) {
            const float bv = s_wv[w2];  const int bf = s_wf[w2];
            Ev = bf ? bv : Ev * bv;
        }
    }
    Ev = Fx ? Vx : Ev * Vx;

    // tile A epilogue
    float T[EPT], e[EPT];
    float prev = Ev;
    #pragma unroll
    for (int k = 0; k < EPT; ++k) {
        T[k] = fA[k] ? 1.0f : prev;
        e[k] = T[k] * aA[k];
        prev = e[k];
    }

    if (idxA + EPT <= n_pts) {
        vf4 w0 = { T[0]-e[0], T[1]-e[1], T[2]-e[2], T[3]-e[3] };
        vf4 w1 = { T[4]-e[4], T[5]-e[5], T[6]-e[6], T[7]-e[7] };
        __builtin_nontemporal_store(w0, reinterpret_cast<vf4*>(weights + idxA));
        __builtin_nontemporal_store(w1, reinterpret_cast<vf4*>(weights + idxA + 4));
    } else {
        #pragma unroll
        for (int k = 0; k < EPT; ++k)
            if (vA[k]) weights[idxA + k] = T[k] - e[k];
    }

    #pragma unroll
    for (int k = 0; k < EPT; ++k) {
        if (vA[k] && rA[k] != rA[k + 1]) {
            alphainv[rA[k]] = e[k];
            for (int q = rA[k] + 1; q < rA[k + 1]; ++q) alphainv[q] = 1.0f;
        }
    }
    if (idxA == 0) {
        for (int q = 0; q < rA[0]; ++q) alphainv[q] = 1.0f;
    }

    if (t == 255) s_tail = e[EPT - 1];   // trailing transmittance of tile A

    // ================= tile B (no lookback; carry = s_tail) ===============
    if (haveB) {
        __syncthreads();                         // barrier B0: s_tail ready

        float aB[EPT]; int fB[EPT];
        #pragma unroll
        for (int k = 0; k < EPT; ++k) {
            const float av = oma(dB[k], sh2, negc, fast);
            aB[k] = vB[k] ? av : 1.0f;
            fB[k] = (k == 0) ? (rB[0] != rprevB) : (rB[k] != rB[k - 1]);
        }

        float Vb = aB[0];  int Fb = fB[0];
        #pragma unroll
        for (int k = 1; k < EPT; ++k) {
            Vb = fB[k] ? aB[k] : Vb * aB[k];
            Fb |= fB[k];
        }

        float Vib = Vb;  int Fib = Fb;
        seg_step<0x111, 0xF>(Vib, Fib);
        seg_step<0x112, 0xF>(Vib, Fib);
        seg_step<0x114, 0xF>(Vib, Fib);
        seg_step<0x118, 0xF>(Vib, Fib);
        seg_step<0x142, 0xA>(Vib, Fib);
        seg_step<0x143, 0xC>(Vib, Fib);

        if (lane == 63) { s_wv[wid] = Vib; s_wf[wid] = Fib; }
        __syncthreads();                         // barrier B1

        float Vxb = __shfl_up(Vib, 1, 64);
        int   Fxb = __shfl_up(Fib, 1, 64);
        if (lane == 0) { Vxb = 1.0f; Fxb = 0; }

        float Evb = s_tail;                      // carry from tile A
        #pragma unroll
        for (int w2 = 0; w2 < 3; ++w2) {
            if (w2 < wid) {
                const float bv = s_wv[w2];  const int bf = s_wf[w2];
                Evb = bf ? bv : Evb * bv;
            }
        }
        Evb = Fxb ? Vxb : Evb * Vxb;

        float Tb[EPT], eb[EPT];
        float prevb = Evb;
        #pragma unroll
        for (int k = 0; k < EPT; ++k) {
            Tb[k] = fB[k] ? 1.0f : prevb;
            eb[k] = Tb[k] * aB[k];
            prevb = eb[k];
        }

        if (idxB + EPT <= n_pts) {
            vf4 w0 = { Tb[0]-eb[0], Tb[1]-eb[1], Tb[2]-eb[2], Tb[3]-eb[3] };
            vf4 w1 = { Tb[4]-eb[4], Tb[5]-eb[5], Tb[6]-eb[6], Tb[7]-eb[7] };
            __builtin_nontemporal_store(w0, reinterpret_cast<vf4*>(weights + idxB));
            __builtin_nontemporal_store(w1, reinterpret_cast<vf4*>(weights + idxB + 4));
        } else {
            #pragma unroll
            for (int k = 0; k < EPT; ++k)
                if (vB[k]) weights[idxB + k] = Tb[k] - eb[k];
        }

        #pragma unroll
        for (int k = 0; k < EPT; ++k) {
            if (vB[k] && rB[k] != rB[k + 1]) {
                alphainv[rB[k]] = eb[k];
                for (int q = rB[k] + 1; q < rB[k + 1]; ++q) alphainv[q] = 1.0f;
            }
        }
    }
}

extern "C" void kernel_launch(void* const* d_in, const int* in_sizes, int n_in,
                              void* d_out, int out_size, void* d_ws, size_t ws_size,
                              hipStream_t stream) {
    const float* density  = (const float*)d_in[0];
    const float* shift    = (const float*)d_in[1];   // 1-element array
    const float* interval = (const float*)d_in[2];   // 1-element array
    const int*   ray_id   = (const int*)d_in[3];
    const int n_pts  = in_sizes[0];
    const int n_rays = out_size - n_pts;

    float* weights  = (float*)d_out;              // [n_pts]
    float* alphainv = (float*)d_out + n_pts;      // [n_rays]

    const int grid = (n_pts + BPTS - 1) / BPTS;
    fused_alpha_weights<<<grid, 256, 0, stream>>>(
        density, ray_id, shift, interval, weights, alphainv, n_pts, n_rays);
}

// Round 15
// 22.628 us; speedup vs baseline: 1.0973x; 1.0973x over previous
//
#include <hip/hip_runtime.h>
#include <math.h>

// ---------------------------------------------------------------------------
// DirectVoxGO Raw2Alpha + Alphas2Weights (forward), single fused kernel.
//
// outputs (concatenated in d_out, float32):
//   weights[n_pts]         = alpha_j * T_j,  T_j = prod_{k<j} (1-alpha_k)
//   alphainv_last[n_rays]  = prod over ray of (1-alpha)  (empty rays -> 1.0)
//
// Structure (R10, the measured optimum of this family): 1 block (256 thr)
// per 2048 consecutive points, 8 pts/thread, ALL loads issued up front,
// XCD-aware bijective block swizzle (lookback window L2-resident),
// segmented multiplicative scan: thread-local fold -> wave64 DPP (value,
// flag) scan -> 4-wave LDS combine -> local head-carry fold (2 barriers).
// Neighbor ray-ids via intra-wave shuffles (register-adjacent data) instead
// of strided global gathers; only lanes 0/63 load the wave-boundary ids.
// ---------------------------------------------------------------------------

#define LOG2E 1.4426950408889634f
#define EPT   8                     // elements per thread (VGPR-safe)
#define BPTS  (256 * EPT)           // points per block = 2048
#define WIN   256                   // lookback window width
#define NXCD  8

typedef float vf4 __attribute__((ext_vector_type(4)));

__device__ __forceinline__ float exp2f_(float x) { return __builtin_amdgcn_exp2f(x); }
__device__ __forceinline__ float log2f_(float x) { return __builtin_amdgcn_logf(x); }
__device__ __forceinline__ float rsqf_(float x)  { return __builtin_amdgcn_rsqf(x); }

__device__ __forceinline__ float oma(float d, float sh2, float negc, bool fast) {
    const float y = fmaf(d, LOG2E, sh2);
    if (fast) return rsqf_(1.0f + exp2f_(y));
    const float sp = fmaxf(y, 0.f) + log2f_(1.f + exp2f_(-fabsf(y)));
    return exp2f_(negc * sp);
}

// Segmented-scan DPP step: combine src (earlier lanes, identity (1,0) when
// out-of-row/masked) into (V,F):  V = F ? V : Vs*V;  F |= Fs.
template <int CTRL, int RM>
__device__ __forceinline__ void seg_step(float& V, int& F) {
    const int vs_i = __builtin_amdgcn_update_dpp(
        0x3f800000, __builtin_bit_cast(int, V), CTRL, RM, 0xF, false);
    const int fs = __builtin_amdgcn_update_dpp(0, F, CTRL, RM, 0xF, false);
    const float vs = __builtin_bit_cast(float, vs_i);
    V = F ? V : vs * V;
    F = F | fs;
}

// Full-wave product, result broadcast to all lanes.
__device__ __forceinline__ float wave_prod_bcast(float x) {
#define STEPP(CTRL, RM)                                                        \
    { int t_ = __builtin_amdgcn_update_dpp(0x3f800000,                         \
          __builtin_bit_cast(int, x), CTRL, RM, 0xF, false);                   \
      x *= __builtin_bit_cast(float, t_); }
    STEPP(0x111, 0xF) STEPP(0x112, 0xF) STEPP(0x114, 0xF)
    STEPP(0x118, 0xF) STEPP(0x142, 0xA) STEPP(0x143, 0xC)
#undef STEPP
    return __builtin_bit_cast(float,
        __builtin_amdgcn_readlane(__builtin_bit_cast(int, x), 63));
}

// Full-wave int max, result broadcast to all lanes.
__device__ __forceinline__ int wave_imax_bcast(int x) {
#define STEPM(CTRL, RM)                                                        \
    { int t_ = __builtin_amdgcn_update_dpp((int)0x80000000, x, CTRL, RM,       \
                                           0xF, false);                        \
      x = (x > t_) ? x : t_; }
    STEPM(0x111, 0xF) STEPM(0x112, 0xF) STEPM(0x114, 0xF)
    STEPM(0x118, 0xF) STEPM(0x142, 0xA) STEPM(0x143, 0xC)
#undef STEPM
    return __builtin_amdgcn_readlane(x, 63);
}

__global__ void __launch_bounds__(256)
fused_alpha_weights(const float* __restrict__ density,
                    const int*   __restrict__ ray_id,
                    const float* __restrict__ shift_p,
                    const float* __restrict__ interval_p,
                    float* __restrict__ weights,
                    float* __restrict__ alphainv,
                    int n_pts, int n_rays) {
    __shared__ float s_wv[4];
    __shared__ int   s_wf[4];
    __shared__ float s_red[4];
    __shared__ int   s_redi[4];

    const int t    = threadIdx.x;
    const int lane = t & 63;
    const int wid  = t >> 6;

    // XCD-aware bijective swizzle (m204): XCD k owns a contiguous data chunk,
    // so data-neighbor blocks are consecutive launches on the SAME XCD.
    const int nwg  = gridDim.x;
    const int orig = blockIdx.x;
    const int qq   = nwg / NXCD, rr = nwg % NXCD;
    const int xcd  = orig % NXCD;
    const int blk  = (xcd < rr ? xcd * (qq + 1) : rr * (qq + 1) + (xcd - rr) * qq)
                   + orig / NXCD;

    const int base = blk * BPTS;
    const int idx0 = base + t * EPT;

    const float shift = shift_p[0];
    const float c     = interval_p[0];
    const float sh2   = shift * LOG2E;
    const float negc  = -c;
    const bool  fast  = (c == 0.5f);

    // ================= phase 0: issue ALL loads up front =================
    int r[EPT + 1]; float d[EPT]; bool v[EPT];
    if (idx0 + EPT <= n_pts) {
        const int4   ri0 = *reinterpret_cast<const int4*>(ray_id + idx0);
        const int4   ri1 = *reinterpret_cast<const int4*>(ray_id + idx0 + 4);
        const float4 de0 = *reinterpret_cast<const float4*>(density + idx0);
        const float4 de1 = *reinterpret_cast<const float4*>(density + idx0 + 4);
        r[0] = ri0.x; r[1] = ri0.y; r[2] = ri0.z; r[3] = ri0.w;
        r[4] = ri1.x; r[5] = ri1.y; r[6] = ri1.z; r[7] = ri1.w;
        d[0] = de0.x; d[1] = de0.y; d[2] = de0.z; d[3] = de0.w;
        d[4] = de1.x; d[5] = de1.y; d[6] = de1.z; d[7] = de1.w;
        #pragma unroll
        for (int k = 0; k < EPT; ++k) v[k] = true;
    } else {
        #pragma unroll
        for (int k = 0; k < EPT; ++k) {
            const int i = idx0 + k;
            v[k] = (i < n_pts);
            r[k] = v[k] ? ray_id[i] : n_rays;    // sentinel past-end ray
            d[k] = v[k] ? density[i] : 0.0f;
        }
    }

    // wave-boundary neighbor ids: only lanes 0/63 touch memory (L1-hot lines)
    int rprev_edge = -1;
    if (lane == 0 && idx0 > 0 && idx0 <= n_pts) rprev_edge = ray_id[idx0 - 1];
    int rnext_edge = n_rays;
    if (lane == 63 && idx0 + EPT < n_pts) rnext_edge = ray_id[idx0 + EPT];

    int w_id = 0; float w_den = 0.0f; int rfirst = 0;
    if (base > 0) {                              // speculative lookback window
        const int wi = base - WIN + t;
        w_id   = ray_id[wi];
        w_den  = density[wi];
        rfirst = ray_id[base];                   // ray active at block head
    }

    // neighbor ray ids from adjacent lanes' registers (no strided gathers)
    const int rp_sh = __shfl_up(r[EPT - 1], 1, 64);
    const int rprev = (lane > 0) ? rp_sh : rprev_edge;
    const int rn_sh = __shfl_down(r[0], 1, 64);
    r[EPT] = (lane < 63) ? rn_sh : rnext_edge;

    // ================= phase 1: per-element values & flags =================
    float a[EPT]; int f[EPT];
    #pragma unroll
    for (int k = 0; k < EPT; ++k) {
        const float av = oma(d[k], sh2, negc, fast);
        a[k] = v[k] ? av : 1.0f;
        f[k] = (k == 0) ? (r[0] != rprev) : (r[k] != r[k - 1]);
    }

    // thread-local (V,F) fold over EPT elements
    float V = a[0];  int F = f[0];
    #pragma unroll
    for (int k = 1; k < EPT; ++k) {
        V = f[k] ? a[k] : V * a[k];
        F |= f[k];
    }

    // wave64 inclusive segmented scan (DPP, VALU-only)
    float Vi = V;  int Fi = F;
    seg_step<0x111, 0xF>(Vi, Fi);   // row_shr:1
    seg_step<0x112, 0xF>(Vi, Fi);   // row_shr:2
    seg_step<0x114, 0xF>(Vi, Fi);   // row_shr:4
    seg_step<0x118, 0xF>(Vi, Fi);   // row_shr:8
    seg_step<0x142, 0xA>(Vi, Fi);   // row_bcast:15 -> rows 1,3
    seg_step<0x143, 0xC>(Vi, Fi);   // row_bcast:31 -> rows 2,3

    // ================= phase 2: cross-wave + head carry (2 barriers) ======
    if (lane == 63) { s_wv[wid] = Vi; s_wf[wid] = Fi; }
    if (base > 0) {
        const int cand = (w_id != rfirst) ? t : -1;
        const int wm = wave_imax_bcast(cand);
        if (lane == 0) s_redi[wid] = wm;
    }
    __syncthreads();                             // barrier 1

    float carry0 = 1.0f;
    if (base > 0) {
        int m = s_redi[0];
        m = (s_redi[1] > m) ? s_redi[1] : m;
        m = (s_redi[2] > m) ? s_redi[2] : m;
        m = (s_redi[3] > m) ? s_redi[3] : m;
        // m >= 0: ray head at base-WIN+m+1; window product over (m, WIN).
        float aa = oma(w_den, sh2, negc, fast);
        if (m >= 0 && t <= m) aa = 1.0f;
        const float wp = wave_prod_bcast(aa);
        if (lane == 0) s_red[wid] = wp;
        __syncthreads();                         // barrier 2
        carry0 = s_red[0] * s_red[1] * s_red[2] * s_red[3];

        if (m < 0) {                             // freak ray: walk further back
            int lo = base - WIN;                 // [s0, lo) still missing
            int s0 = -1;
            while (s0 < 0) {
                const int wstart = lo - WIN;
                const int i = wstart + t;
                const int vv = (i >= 0) ? ray_id[i] : -1;
                const int c2 = (vv != rfirst) ? t : -1;
                const int wm2 = wave_imax_bcast(c2);
                if (lane == 0) s_redi[wid] = wm2;
                __syncthreads();
                int m2 = s_redi[0];
                m2 = (s_redi[1] > m2) ? s_redi[1] : m2;
                m2 = (s_redi[2] > m2) ? s_redi[2] : m2;
                m2 = (s_redi[3] > m2) ? s_redi[3] : m2;
                __syncthreads();
                if (m2 >= 0) s0 = wstart + m2 + 1; else lo = wstart;
            }
            for (int off = s0; off < base - WIN; off += WIN) {
                const int i = off + t;
                const float aa2 = (i < base - WIN)
                                ? oma(density[i], sh2, negc, fast) : 1.0f;
                const float wp2 = wave_prod_bcast(aa2);
                if (lane == 0) s_red[wid] = wp2;
                __syncthreads();
                carry0 *= s_red[0] * s_red[1] * s_red[2] * s_red[3];
                __syncthreads();
            }
        }
    }

    // exclusive pair for this thread (within wave)
    float Vx = __shfl_up(Vi, 1, 64);
    int   Fx = __shfl_up(Fi, 1, 64);
    if (lane == 0) { Vx = 1.0f; Fx = 0; }

    // fold block head carry + lower waves + lower lanes
    float Ev = carry0;
    #pragma unroll
    for (int w2 = 0; w2 < 3; ++w2) {
        if (w2 < wid) {
            const float bv = s_wv[w2];  const int bf = s_wf[w2];
            Ev = bf ? bv : Ev * bv;
        }
    }
    Ev = Fx ? Vx : Ev * Vx;            // exclusive transmittance at elem 0

    // ================= phase 3: T chain, weights, alphainv =================
    float T[EPT], e[EPT];
    float prev = Ev;
    #pragma unroll
    for (int k = 0; k < EPT; ++k) {
        T[k] = f[k] ? 1.0f : prev;
        e[k] = T[k] * a[k];
        prev = e[k];
    }

    if (idx0 + EPT <= n_pts) {
        vf4 w0 = { T[0] - e[0], T[1] - e[1], T[2] - e[2], T[3] - e[3] };
        vf4 w1 = { T[4] - e[4], T[5] - e[5], T[6] - e[6], T[7] - e[7] };
        __builtin_nontemporal_store(w0, reinterpret_cast<vf4*>(weights + idx0));
        __builtin_nontemporal_store(w1, reinterpret_cast<vf4*>(weights + idx0 + 4));
    } else {
        #pragma unroll
        for (int k = 0; k < EPT; ++k)
            if (v[k]) weights[idx0 + k] = T[k] - e[k];
    }

    // segment ends: write alphainv for ending ray; fill empty rays in gaps
    #pragma unroll
    for (int k = 0; k < EPT; ++k) {
        if (v[k] && r[k] != r[k + 1]) {
            alphainv[r[k]] = e[k];
            for (int q = r[k] + 1; q < r[k + 1]; ++q) alphainv[q] = 1.0f;
        }
    }
    if (idx0 == 0) {                    // rays before the first point
        for (int q = 0; q < r[0]; ++q) alphainv[q] = 1.0f;
    }
}

extern "C" void kernel_launch(void* const* d_in, const int* in_sizes, int n_in,
                              void* d_out, int out_size, void* d_ws, size_t ws_size,
                              hipStream_t stream) {
    const float* density  = (const float*)d_in[0];
    const float* shift    = (const float*)d_in[1];   // 1-element array
    const float* interval = (const float*)d_in[2];   // 1-element array
    const int*   ray_id   = (const int*)d_in[3];
    const int n_pts  = in_sizes[0];
    const int n_rays = out_size - n_pts;

    float* weights  = (float*)d_out;              // [n_pts]
    float* alphainv = (float*)d_out + n_pts;      // [n_rays]

    const int grid = (n_pts + BPTS - 1) / BPTS;
    fused_alpha_weights<<<grid, 256, 0, stream>>>(
        density, ray_id, shift, interval, weights, alphainv, n_pts, n_rays);
}